// Round 1
// baseline (218.106 us; speedup 1.0000x reference)
//
#include <hip/hip_runtime.h>

#define EPSV 1e-5f

// ---------- fused stage-1 stats: blocks [0,1024) reduce y, [1024,1280) reduce x ----------
__global__ __launch_bounds__(256) void stats_kernel(const float* __restrict__ y,
                                                    const float* __restrict__ x,
                                                    float* __restrict__ part) {
    int bid = blockIdx.x;
    const float* src = (bid < 1024) ? (y + (size_t)bid * 16384)
                                    : (x + (size_t)(bid - 1024) * 16384);
    const float4* p = (const float4*)src;
    float s = 0.f, ss = 0.f;
    #pragma unroll 8
    for (int i = threadIdx.x; i < 4096; i += 256) {
        float4 v = p[i];
        s  += v.x + v.y + v.z + v.w;
        ss += v.x*v.x + v.y*v.y + v.z*v.z + v.w*v.w;
    }
    for (int off = 32; off > 0; off >>= 1) {
        s  += __shfl_down(s, off);
        ss += __shfl_down(ss, off);
    }
    __shared__ float red[8];
    int wid = threadIdx.x >> 6, lane = threadIdx.x & 63;
    if (lane == 0) { red[wid*2] = s; red[wid*2+1] = ss; }
    __syncthreads();
    if (threadIdx.x == 0) {
        part[bid*2+0] = red[0] + red[2] + red[4] + red[6];
        part[bid*2+1] = red[1] + red[3] + red[5] + red[7];
    }
}

// ---------- fused make_eff: blocks [0,128) Q-side, [128,256) K-side ----------
__global__ __launch_bounds__(64) void make_eff_kernel(const float* __restrict__ qw, const float* __restrict__ qb,
                                                      const float* __restrict__ gyw, const float* __restrict__ gyb,
                                                      const float* __restrict__ kw, const float* __restrict__ kb,
                                                      const float* __restrict__ gxw, const float* __restrict__ gxb,
                                                      const float* __restrict__ part,
                                                      float* __restrict__ WeffQ, float* __restrict__ beffQ,
                                                      float* __restrict__ WeffK, float* __restrict__ beffK) {
    int id = blockIdx.x;
    int isK = id >> 7, b = (id >> 5) & 3, e = id & 31;
    const float* w     = isK ? kw  : qw;
    const float* bias  = isK ? kb  : qb;
    const float* gamma = isK ? gxw : gyw;
    const float* beta  = isK ? gxb : gyb;
    float inv_n = isK ? (1.f/32768.f) : (1.f/131072.f);
    float* W  = isK ? WeffK : WeffQ;
    float* be = isK ? beffK : beffQ;
    float partial = 0.f;
    for (int c = threadIdx.x; c < 256; c += 64) {
        int g = c >> 3, grp = b*32 + g;
        float s = 0.f, ss = 0.f;
        if (isK) {
            #pragma unroll
            for (int k2 = 0; k2 < 2; ++k2) {
                s  += part[(1024 + grp*2 + k2)*2 + 0];
                ss += part[(1024 + grp*2 + k2)*2 + 1];
            }
        } else {
            #pragma unroll
            for (int k2 = 0; k2 < 8; ++k2) {
                s  += part[(grp*8 + k2)*2 + 0];
                ss += part[(grp*8 + k2)*2 + 1];
            }
        }
        float mu = s * inv_n;
        float rs = rsqrtf(fmaf(-mu, mu, ss * inv_n) + EPSV);
        float wc = w[e*256 + c];
        float weff = wc * gamma[c] * rs;
        W[((size_t)b*256 + c)*32 + e] = weff;
        partial += wc * beta[c] - weff * mu;
    }
    for (int off = 32; off > 0; off >>= 1) partial += __shfl_down(partial, off);
    if (threadIdx.x == 0) be[b*32 + e] = partial + bias[e];
}

// ---------- fused 1x1 projection, flat 640-block grid ----------
// bid<512: y->q (b=bid>>7, 128 px-blocks); bid>=512: x->k (b=(bid-512)>>5, 32 px-blocks)
__global__ __launch_bounds__(256) void proj_kernel(const float* __restrict__ y, const float* __restrict__ x,
                                                   const float* __restrict__ WeffQ, const float* __restrict__ beffQ,
                                                   const float* __restrict__ WeffK, const float* __restrict__ beffK,
                                                   float* __restrict__ qbuf, float* __restrict__ kbuf) {
    int bid = blockIdx.x;
    int isX = bid >= 512;
    int lb = isX ? bid - 512 : bid;
    int b    = isX ? (lb >> 5) : (lb >> 7);
    int pxb  = isX ? (lb & 31) : (lb & 127);
    int npix = isX ? 4096 : 16384;
    const float* src   = isX ? x : y;
    const float* WeffT = isX ? WeffK : WeffQ;
    const float* beff  = isX ? beffK : beffQ;
    float* dst = isX ? kbuf : qbuf;

    int pix0 = pxb * 128 + (threadIdx.x & 63) * 2;
    int eg = __builtin_amdgcn_readfirstlane(threadIdx.x >> 6);
    const float* wp = WeffT + (size_t)b*256*32 + eg*8;
    float acc[2][8];
    #pragma unroll
    for (int j = 0; j < 8; ++j) {
        float bv = beff[b*32 + eg*8 + j];
        acc[0][j] = bv; acc[1][j] = bv;
    }
    const float* ysrc = src + (size_t)b*256*npix + pix0;
    #pragma unroll 8
    for (int c = 0; c < 256; ++c) {
        float2 t = *(const float2*)(ysrc + (size_t)c*npix);
        #pragma unroll
        for (int j = 0; j < 8; ++j) {
            float wj = wp[c*32 + j];
            acc[0][j] = fmaf(t.x, wj, acc[0][j]);
            acc[1][j] = fmaf(t.y, wj, acc[1][j]);
        }
    }
    float* dbase = dst + ((size_t)b*npix + pix0)*32 + eg*8;
    #pragma unroll
    for (int px = 0; px < 2; ++px) {
        float4 o0 = {acc[px][0], acc[px][1], acc[px][2], acc[px][3]};
        float4 o1 = {acc[px][4], acc[px][5], acc[px][6], acc[px][7]};
        *(float4*)(dbase + px*32 + 0) = o0;
        *(float4*)(dbase + px*32 + 4) = o1;
    }
}

// ---------- kernel A: attention weights ----------
// Block = 8x8 low-res tile, thread = child (tid = 32h+16u+2w+v).
// Writes attn maps [b][tile(64)][child(256)][25] via LDS bounce (coalesced).
__global__ __launch_bounds__(256) void attn_weights_kernel(const float* __restrict__ q,   // [B][16384][32]
                                                           const float* __restrict__ kk,  // [B][4096][32]
                                                           float* __restrict__ g_attn)    // [B][64][6400]
{
    __shared__ __align__(16) float sK[5184];   // [144 pos][36]
    __shared__ __align__(16) float sA[6400];   // [256 child][25]
    int h0 = blockIdx.y * 8, w0 = blockIdx.x * 8;
    int b = blockIdx.z;
    int tid = threadIdx.x;

    // stage k halo: pos-major, stride 36
    for (int i = tid; i < 1152; i += 256) {
        int pos = i >> 3, e4 = i & 7;
        int r = pos / 12, c = pos - 12*r;
        int gh = h0 + r - 2, gw = w0 + c - 2;
        float4 v = make_float4(0.f, 0.f, 0.f, 0.f);
        if (gh >= 0 && gh < 64 && gw >= 0 && gw < 64)
            v = *(const float4*)(kk + (((size_t)b*4096 + gh*64 + gw)*32 + e4*4));
        *(float4*)&sK[pos*36 + e4*4] = v;
    }

    int h = tid >> 5, u = (tid >> 4) & 1, w = (tid >> 1) & 7, v = tid & 1;

    float qv[32];
    {
        int hh = 2*(h0 + h) + u, ww = 2*(w0 + w) + v;
        const float4* qp = (const float4*)(q + (((size_t)b*16384 + hh*128 + ww)*32));
        #pragma unroll
        for (int i4 = 0; i4 < 8; ++i4) {
            float4 t = qp[i4];
            qv[i4*4+0]=t.x; qv[i4*4+1]=t.y; qv[i4*4+2]=t.z; qv[i4*4+3]=t.w;
        }
    }
    __syncthreads();

    float a[25];
    const float* kbase = &sK[(h*12 + w)*36];
    #pragma unroll
    for (int j = 0; j < 25; ++j) {
        int dy = j / 5, dx = j - 5*dy;
        const float4* kp = (const float4*)(kbase + (dy*12 + dx)*36);
        float acc = 0.f;
        #pragma unroll
        for (int e4 = 0; e4 < 8; ++e4) {
            float4 kv = kp[e4];
            acc = fmaf(qv[e4*4+0], kv.x, acc);
            acc = fmaf(qv[e4*4+1], kv.y, acc);
            acc = fmaf(qv[e4*4+2], kv.z, acc);
            acc = fmaf(qv[e4*4+3], kv.w, acc);
        }
        a[j] = acc;
    }
    {
        float m = -1e30f;
        #pragma unroll
        for (int j = 0; j < 25; ++j) m = fmaxf(m, a[j]);
        float s = 0.f;
        #pragma unroll
        for (int j = 0; j < 25; ++j) { a[j] = __expf(a[j] - m); s += a[j]; }
        float inv = 1.f / s;
        #pragma unroll
        for (int j = 0; j < 25; ++j) sA[tid*25 + j] = a[j] * inv;
    }
    __syncthreads();

    // coalesced copy out: 6400 floats = 1600 float4
    float4* gdst = (float4*)(g_attn + ((size_t)b*64 + blockIdx.y*8 + blockIdx.x)*6400);
    const float4* ssrc = (const float4*)sA;
    for (int i = tid; i < 1600; i += 256) gdst[i] = ssrc[i];
}

// ---------- kernel B: weighted gather (parent-thread restructure) ----------
// grid (8,8,16): bz = b*4 + slab(64 ch). Block = tile.
// Lane map: wave W owns parent rows {2W, 2W+1}; lane = cg*16 + hp*8 + w.
// Each thread keeps all 4 children's 25 attn weights in registers, so one
// ds_read_b128 of x feeds 16 outputs (4 ch x 4 children): 4x fewer LDS reads.
__global__ __launch_bounds__(256) void gather_kernel(const float* __restrict__ g_attn, // [B][64][6400]
                                                     const float* __restrict__ x,      // [B][256][64][64]
                                                     float* __restrict__ out)          // [B][256][128][128]
{
    __shared__ __align__(16) float sAttn[6400];
    __shared__ __align__(16) float sX[2880];   // 144*20
    int h0 = blockIdx.y * 8, w0 = blockIdx.x * 8;
    int b = blockIdx.z >> 2, slab = blockIdx.z & 3;
    int tid = threadIdx.x;

    // stage attn maps
    {
        const float4* gsrc = (const float4*)(g_attn + ((size_t)b*64 + blockIdx.y*8 + blockIdx.x)*6400);
        float4* sdst = (float4*)sAttn;
        for (int i = tid; i < 1600; i += 256) sdst[i] = gsrc[i];
    }
    __syncthreads();

    // thread decomposition: wave W = tid>>6 owns parent rows h in {2W, 2W+1}
    int W    = tid >> 6;
    int lane = tid & 63;
    int cg   = lane >> 4;         // float4 channel group within 16-ch chunk
    int hp   = (lane >> 3) & 1;
    int w    = lane & 7;
    int h    = W*2 + hp;

    // per-thread attention weights for the 4 children of parent (h,w)
    // child id = 32h + 16u + 2w + v ; lane bank spread: 18w mod 32 distinct (8),
    // hp 2-way (free), cg 4-lane broadcast.
    float a4[4][25];
    #pragma unroll
    for (int u = 0; u < 2; ++u) {
        #pragma unroll
        for (int v = 0; v < 2; ++v) {
            const float* ap = &sAttn[(32*h + 16*u + 2*w + v)*25];
            #pragma unroll
            for (int j = 0; j < 25; ++j) a4[u*2+v][j] = ap[j];
        }
    }

    int vbase = (h*12 + w)*20 + cg*4;
    int hh0 = 2*(h0 + h);
    int ww  = 2*(w0 + w);

    for (int c0 = 0; c0 < 64; c0 += 16) {
        __syncthreads();   // previous chunk's sX readers done before restage
        // stage x chunk: 16 ch x 144 pos, pos-inner (coalesced global)
        for (int i = 0; i < 9; ++i) {
            int t = i*256 + tid;
            int cc = t / 144, pos = t - 144*cc;
            int r = pos / 12, cl = pos - 12*r;
            int gh = h0 + r - 2, gw = w0 + cl - 2;
            float val = 0.f;
            if (gh >= 0 && gh < 64 && gw >= 0 && gw < 64)
                val = x[(((size_t)b*256 + slab*64 + c0 + cc)*64 + gh)*64 + gw];
            sX[pos*20 + cc] = val;
        }
        __syncthreads();

        float acc[4][4];   // [ci (channel within float4)][child u*2+v]
        #pragma unroll
        for (int ci = 0; ci < 4; ++ci)
            #pragma unroll
            for (int c = 0; c < 4; ++c) acc[ci][c] = 0.f;

        #pragma unroll
        for (int j = 0; j < 25; ++j) {
            int dy = j / 5, dx = j - 5*dy;
            float4 xv = *(const float4*)&sX[vbase + (dy*12 + dx)*20];
            #pragma unroll
            for (int c = 0; c < 4; ++c) {
                float aw = a4[c][j];
                acc[0][c] = fmaf(aw, xv.x, acc[0][c]);
                acc[1][c] = fmaf(aw, xv.y, acc[1][c]);
                acc[2][c] = fmaf(aw, xv.z, acc[2][c]);
                acc[3][c] = fmaf(aw, xv.w, acc[3][c]);
            }
        }

        // write 4 channels x 4 children; (v0,v1) pair = contiguous float2,
        // 8 w-lanes form contiguous 64B segments.
        #pragma unroll
        for (int ci = 0; ci < 4; ++ci) {
            int ch = slab*64 + c0 + cg*4 + ci;
            #pragma unroll
            for (int u = 0; u < 2; ++u) {
                float2 o = make_float2(acc[ci][u*2+0], acc[ci][u*2+1]);
                *(float2*)&out[(((size_t)b*256 + ch)*128 + (hh0 + u))*128 + ww] = o;
            }
        }
    }
}

extern "C" void kernel_launch(void* const* d_in, const int* in_sizes, int n_in,
                              void* d_out, int out_size, void* d_ws, size_t ws_size,
                              hipStream_t stream) {
    const float* y   = (const float*)d_in[0];
    const float* x   = (const float*)d_in[1];
    const float* gyw = (const float*)d_in[2];
    const float* gyb = (const float*)d_in[3];
    const float* gxw = (const float*)d_in[4];
    const float* gxb = (const float*)d_in[5];
    const float* qw  = (const float*)d_in[6];
    const float* qb  = (const float*)d_in[7];
    const float* kw  = (const float*)d_in[8];
    const float* kb  = (const float*)d_in[9];
    float* out = (float*)d_out;
    float* ws  = (float*)d_ws;

    float* part   = ws;              // 2560
    float* WeffQ  = ws + 2560;       // 32768
    float* beffQ  = ws + 35328;      // 128
    float* WeffK  = ws + 35456;      // 32768
    float* beffK  = ws + 68224;      // 128
    float* qbuf   = ws + 68352;      // 4*16384*32 = 2097152
    float* kbuf   = ws + 2165504;    // 4*4096*32  = 524288
    float* attnbf = ws + 2689792;    // 4*64*6400  = 1638400  (total ~17.3 MB)

    stats_kernel<<<1280, 256, 0, stream>>>(y, x, part);
    make_eff_kernel<<<256, 64, 0, stream>>>(qw, qb, gyw, gyb, kw, kb, gxw, gxb,
                                            part, WeffQ, beffQ, WeffK, beffK);
    proj_kernel<<<640, 256, 0, stream>>>(y, x, WeffQ, beffQ, WeffK, beffK, qbuf, kbuf);
    attn_weights_kernel<<<dim3(8, 8, 4), 256, 0, stream>>>(qbuf, kbuf, attnbf);
    gather_kernel<<<dim3(8, 8, 16), 256, 0, stream>>>(attnbf, x, out);
}

// Round 2
// 210.677 us; speedup vs baseline: 1.0353x; 1.0353x over previous
//
#include <hip/hip_runtime.h>

#define EPSV 1e-5f

// ---------- fused stage-1 stats: blocks [0,1024) reduce y, [1024,1280) reduce x ----------
__global__ __launch_bounds__(256) void stats_kernel(const float* __restrict__ y,
                                                    const float* __restrict__ x,
                                                    float* __restrict__ part) {
    int bid = blockIdx.x;
    const float* src = (bid < 1024) ? (y + (size_t)bid * 16384)
                                    : (x + (size_t)(bid - 1024) * 16384);
    const float4* p = (const float4*)src;
    float s = 0.f, ss = 0.f;
    #pragma unroll 8
    for (int i = threadIdx.x; i < 4096; i += 256) {
        float4 v = p[i];
        s  += v.x + v.y + v.z + v.w;
        ss += v.x*v.x + v.y*v.y + v.z*v.z + v.w*v.w;
    }
    for (int off = 32; off > 0; off >>= 1) {
        s  += __shfl_down(s, off);
        ss += __shfl_down(ss, off);
    }
    __shared__ float red[8];
    int wid = threadIdx.x >> 6, lane = threadIdx.x & 63;
    if (lane == 0) { red[wid*2] = s; red[wid*2+1] = ss; }
    __syncthreads();
    if (threadIdx.x == 0) {
        part[bid*2+0] = red[0] + red[2] + red[4] + red[6];
        part[bid*2+1] = red[1] + red[3] + red[5] + red[7];
    }
}

// ---------- fused make_eff: blocks [0,128) Q-side, [128,256) K-side ----------
__global__ __launch_bounds__(64) void make_eff_kernel(const float* __restrict__ qw, const float* __restrict__ qb,
                                                      const float* __restrict__ gyw, const float* __restrict__ gyb,
                                                      const float* __restrict__ kw, const float* __restrict__ kb,
                                                      const float* __restrict__ gxw, const float* __restrict__ gxb,
                                                      const float* __restrict__ part,
                                                      float* __restrict__ WeffQ, float* __restrict__ beffQ,
                                                      float* __restrict__ WeffK, float* __restrict__ beffK) {
    int id = blockIdx.x;
    int isK = id >> 7, b = (id >> 5) & 3, e = id & 31;
    const float* w     = isK ? kw  : qw;
    const float* bias  = isK ? kb  : qb;
    const float* gamma = isK ? gxw : gyw;
    const float* beta  = isK ? gxb : gyb;
    float inv_n = isK ? (1.f/32768.f) : (1.f/131072.f);
    float* W  = isK ? WeffK : WeffQ;
    float* be = isK ? beffK : beffQ;
    float partial = 0.f;
    for (int c = threadIdx.x; c < 256; c += 64) {
        int g = c >> 3, grp = b*32 + g;
        float s = 0.f, ss = 0.f;
        if (isK) {
            #pragma unroll
            for (int k2 = 0; k2 < 2; ++k2) {
                s  += part[(1024 + grp*2 + k2)*2 + 0];
                ss += part[(1024 + grp*2 + k2)*2 + 1];
            }
        } else {
            #pragma unroll
            for (int k2 = 0; k2 < 8; ++k2) {
                s  += part[(grp*8 + k2)*2 + 0];
                ss += part[(grp*8 + k2)*2 + 1];
            }
        }
        float mu = s * inv_n;
        float rs = rsqrtf(fmaf(-mu, mu, ss * inv_n) + EPSV);
        float wc = w[e*256 + c];
        float weff = wc * gamma[c] * rs;
        W[((size_t)b*256 + c)*32 + e] = weff;
        partial += wc * beta[c] - weff * mu;
    }
    for (int off = 32; off > 0; off >>= 1) partial += __shfl_down(partial, off);
    if (threadIdx.x == 0) be[b*32 + e] = partial + bias[e];
}

// ---------- fused 1x1 projection, flat 640-block grid ----------
// bid<512: y->q (b=bid>>7, 128 px-blocks); bid>=512: x->k (b=(bid-512)>>5, 32 px-blocks)
__global__ __launch_bounds__(256) void proj_kernel(const float* __restrict__ y, const float* __restrict__ x,
                                                   const float* __restrict__ WeffQ, const float* __restrict__ beffQ,
                                                   const float* __restrict__ WeffK, const float* __restrict__ beffK,
                                                   float* __restrict__ qbuf, float* __restrict__ kbuf) {
    int bid = blockIdx.x;
    int isX = bid >= 512;
    int lb = isX ? bid - 512 : bid;
    int b    = isX ? (lb >> 5) : (lb >> 7);
    int pxb  = isX ? (lb & 31) : (lb & 127);
    int npix = isX ? 4096 : 16384;
    const float* src   = isX ? x : y;
    const float* WeffT = isX ? WeffK : WeffQ;
    const float* beff  = isX ? beffK : beffQ;
    float* dst = isX ? kbuf : qbuf;

    int pix0 = pxb * 128 + (threadIdx.x & 63) * 2;
    int eg = __builtin_amdgcn_readfirstlane(threadIdx.x >> 6);
    const float* wp = WeffT + (size_t)b*256*32 + eg*8;
    float acc[2][8];
    #pragma unroll
    for (int j = 0; j < 8; ++j) {
        float bv = beff[b*32 + eg*8 + j];
        acc[0][j] = bv; acc[1][j] = bv;
    }
    const float* ysrc = src + (size_t)b*256*npix + pix0;
    #pragma unroll 8
    for (int c = 0; c < 256; ++c) {
        float2 t = *(const float2*)(ysrc + (size_t)c*npix);
        #pragma unroll
        for (int j = 0; j < 8; ++j) {
            float wj = wp[c*32 + j];
            acc[0][j] = fmaf(t.x, wj, acc[0][j]);
            acc[1][j] = fmaf(t.y, wj, acc[1][j]);
        }
    }
    float* dbase = dst + ((size_t)b*npix + pix0)*32 + eg*8;
    #pragma unroll
    for (int px = 0; px < 2; ++px) {
        float4 o0 = {acc[px][0], acc[px][1], acc[px][2], acc[px][3]};
        float4 o1 = {acc[px][4], acc[px][5], acc[px][6], acc[px][7]};
        *(float4*)(dbase + px*32 + 0) = o0;
        *(float4*)(dbase + px*32 + 4) = o1;
    }
}

// ---------- kernel A: attention weights ----------
// Block = 8x8 low-res tile, thread = child (tid = 32h+16u+2w+v).
// Writes attn maps TRANSPOSED [b][tile(64)][25 tap][256 child] so the gather
// kernel can read per-thread weights with coalesced global dword loads.
__global__ __launch_bounds__(256) void attn_weights_kernel(const float* __restrict__ q,   // [B][16384][32]
                                                           const float* __restrict__ kk,  // [B][4096][32]
                                                           float* __restrict__ g_attn)    // [B][64][25][256]
{
    __shared__ __align__(16) float sK[5184];   // [144 pos][36]
    __shared__ __align__(16) float sA[6400];   // [25 tap][256 child]
    int h0 = blockIdx.y * 8, w0 = blockIdx.x * 8;
    int b = blockIdx.z;
    int tid = threadIdx.x;

    // stage k halo: pos-major, stride 36
    for (int i = tid; i < 1152; i += 256) {
        int pos = i >> 3, e4 = i & 7;
        int r = pos / 12, c = pos - 12*r;
        int gh = h0 + r - 2, gw = w0 + c - 2;
        float4 v = make_float4(0.f, 0.f, 0.f, 0.f);
        if (gh >= 0 && gh < 64 && gw >= 0 && gw < 64)
            v = *(const float4*)(kk + (((size_t)b*4096 + gh*64 + gw)*32 + e4*4));
        *(float4*)&sK[pos*36 + e4*4] = v;
    }

    int h = tid >> 5, u = (tid >> 4) & 1, w = (tid >> 1) & 7, v = tid & 1;

    float qv[32];
    {
        int hh = 2*(h0 + h) + u, ww = 2*(w0 + w) + v;
        const float4* qp = (const float4*)(q + (((size_t)b*16384 + hh*128 + ww)*32));
        #pragma unroll
        for (int i4 = 0; i4 < 8; ++i4) {
            float4 t = qp[i4];
            qv[i4*4+0]=t.x; qv[i4*4+1]=t.y; qv[i4*4+2]=t.z; qv[i4*4+3]=t.w;
        }
    }
    __syncthreads();

    float a[25];
    const float* kbase = &sK[(h*12 + w)*36];
    #pragma unroll
    for (int j = 0; j < 25; ++j) {
        int dy = j / 5, dx = j - 5*dy;
        const float4* kp = (const float4*)(kbase + (dy*12 + dx)*36);
        float acc = 0.f;
        #pragma unroll
        for (int e4 = 0; e4 < 8; ++e4) {
            float4 kv = kp[e4];
            acc = fmaf(qv[e4*4+0], kv.x, acc);
            acc = fmaf(qv[e4*4+1], kv.y, acc);
            acc = fmaf(qv[e4*4+2], kv.z, acc);
            acc = fmaf(qv[e4*4+3], kv.w, acc);
        }
        a[j] = acc;
    }
    {
        float m = -1e30f;
        #pragma unroll
        for (int j = 0; j < 25; ++j) m = fmaxf(m, a[j]);
        float s = 0.f;
        #pragma unroll
        for (int j = 0; j < 25; ++j) { a[j] = __expf(a[j] - m); s += a[j]; }
        float inv = 1.f / s;
        // transposed store: tap-major, child-inner (conflict-free: lanes consecutive)
        #pragma unroll
        for (int j = 0; j < 25; ++j) sA[j*256 + tid] = a[j] * inv;
    }
    __syncthreads();

    // coalesced copy out: 6400 floats = 1600 float4
    float4* gdst = (float4*)(g_attn + ((size_t)b*64 + blockIdx.y*8 + blockIdx.x)*6400);
    const float4* ssrc = (const float4*)sA;
    for (int i = tid; i < 1600; i += 256) gdst[i] = ssrc[i];
}

// ---------- kernel B: weighted gather (round-0 structure, no sAttn) ----------
// grid (8,8,16): bz = b*4 + slab(64 ch). Block = tile, thread = child.
// Attn weights come straight from global (transposed layout -> coalesced dword
// loads, one per tap, reused across all 4 chunks). LDS = sX only (11.5 KB)
// -> 8 blocks/CU (wave-limited), whole grid co-resident.
// sX [144 pos][16 ch] stride 20 -> b128 reads <=2-way + 4-child broadcast.
__global__ __launch_bounds__(256) void gather_kernel(const float* __restrict__ g_attn, // [B][64][25][256]
                                                     const float* __restrict__ x,      // [B][256][64][64]
                                                     float* __restrict__ out)          // [B][256][128][128]
{
    __shared__ __align__(16) float sX[2880];   // 144*20
    int h0 = blockIdx.y * 8, w0 = blockIdx.x * 8;
    int b = blockIdx.z >> 2, slab = blockIdx.z & 3;
    int tid = threadIdx.x;

    // per-thread attention weights: coalesced global loads (lane = child)
    float a[25];
    {
        const float* abase = g_attn + ((size_t)b*64 + blockIdx.y*8 + blockIdx.x)*6400 + tid;
        #pragma unroll
        for (int j = 0; j < 25; ++j) a[j] = abase[j*256];
    }

    int h = tid >> 5, u = (tid >> 4) & 1, w = (tid >> 1) & 7, v = tid & 1;
    int hh = 2*(h0 + h) + u, ww = 2*(w0 + w) + v;
    int vbase = (h*12 + w)*20;

    for (int c0 = 0; c0 < 64; c0 += 16) {
        if (c0) __syncthreads();
        // stage x chunk: 16 ch x 144 pos, pos-inner (coalesced global)
        for (int i = 0; i < 9; ++i) {
            int t = i*256 + tid;
            int cc = t / 144, pos = t - 144*cc;
            int r = pos / 12, cl = pos - 12*r;
            int gh = h0 + r - 2, gw = w0 + cl - 2;
            float val = 0.f;
            if (gh >= 0 && gh < 64 && gw >= 0 && gw < 64)
                val = x[(((size_t)b*256 + slab*64 + c0 + cc)*64 + gh)*64 + gw];
            sX[pos*20 + cc] = val;
        }
        __syncthreads();

        #pragma unroll
        for (int g = 0; g < 4; ++g) {
            float o0 = 0.f, o1 = 0.f, o2 = 0.f, o3 = 0.f;
            const float* xb = &sX[vbase + g*4];
            #pragma unroll
            for (int j = 0; j < 25; ++j) {
                int dy = j / 5, dx = j - 5*dy;
                float4 xv = *(const float4*)(xb + (dy*12 + dx)*20);
                float aw = a[j];
                o0 = fmaf(aw, xv.x, o0);
                o1 = fmaf(aw, xv.y, o1);
                o2 = fmaf(aw, xv.z, o2);
                o3 = fmaf(aw, xv.w, o3);
            }
            size_t ob = (((size_t)b*256 + slab*64 + c0 + g*4)*128 + hh)*128 + ww;
            out[ob]           = o0;
            out[ob + 16384]   = o1;
            out[ob + 32768]   = o2;
            out[ob + 49152]   = o3;
        }
    }
}

extern "C" void kernel_launch(void* const* d_in, const int* in_sizes, int n_in,
                              void* d_out, int out_size, void* d_ws, size_t ws_size,
                              hipStream_t stream) {
    const float* y   = (const float*)d_in[0];
    const float* x   = (const float*)d_in[1];
    const float* gyw = (const float*)d_in[2];
    const float* gyb = (const float*)d_in[3];
    const float* gxw = (const float*)d_in[4];
    const float* gxb = (const float*)d_in[5];
    const float* qw  = (const float*)d_in[6];
    const float* qb  = (const float*)d_in[7];
    const float* kw  = (const float*)d_in[8];
    const float* kb  = (const float*)d_in[9];
    float* out = (float*)d_out;
    float* ws  = (float*)d_ws;

    float* part   = ws;              // 2560
    float* WeffQ  = ws + 2560;       // 32768
    float* beffQ  = ws + 35328;      // 128
    float* WeffK  = ws + 35456;      // 32768
    float* beffK  = ws + 68224;      // 128
    float* qbuf   = ws + 68352;      // 4*16384*32 = 2097152
    float* kbuf   = ws + 2165504;    // 4*4096*32  = 524288
    float* attnbf = ws + 2689792;    // 4*64*6400  = 1638400  (total ~17.3 MB)

    stats_kernel<<<1280, 256, 0, stream>>>(y, x, part);
    make_eff_kernel<<<256, 64, 0, stream>>>(qw, qb, gyw, gyb, kw, kb, gxw, gxb,
                                            part, WeffQ, beffQ, WeffK, beffK);
    proj_kernel<<<640, 256, 0, stream>>>(y, x, WeffQ, beffQ, WeffK, beffK, qbuf, kbuf);
    attn_weights_kernel<<<dim3(8, 8, 4), 256, 0, stream>>>(qbuf, kbuf, attnbf);
    gather_kernel<<<dim3(8, 8, 16), 256, 0, stream>>>(attnbf, x, out);
}

// Round 3
// 204.151 us; speedup vs baseline: 1.0684x; 1.0320x over previous
//
#include <hip/hip_runtime.h>

#define EPSV 1e-5f

// ---------- fused stage-1 stats: blocks [0,1024) reduce y, [1024,1280) reduce x ----------
__global__ __launch_bounds__(256) void stats_kernel(const float* __restrict__ y,
                                                    const float* __restrict__ x,
                                                    float* __restrict__ part) {
    int bid = blockIdx.x;
    const float* src = (bid < 1024) ? (y + (size_t)bid * 16384)
                                    : (x + (size_t)(bid - 1024) * 16384);
    const float4* p = (const float4*)src;
    float s = 0.f, ss = 0.f;
    #pragma unroll 8
    for (int i = threadIdx.x; i < 4096; i += 256) {
        float4 v = p[i];
        s  += v.x + v.y + v.z + v.w;
        ss += v.x*v.x + v.y*v.y + v.z*v.z + v.w*v.w;
    }
    for (int off = 32; off > 0; off >>= 1) {
        s  += __shfl_down(s, off);
        ss += __shfl_down(ss, off);
    }
    __shared__ float red[8];
    int wid = threadIdx.x >> 6, lane = threadIdx.x & 63;
    if (lane == 0) { red[wid*2] = s; red[wid*2+1] = ss; }
    __syncthreads();
    if (threadIdx.x == 0) {
        part[bid*2+0] = red[0] + red[2] + red[4] + red[6];
        part[bid*2+1] = red[1] + red[3] + red[5] + red[7];
    }
}

// ---------- fused make_eff: blocks [0,128) Q-side, [128,256) K-side ----------
__global__ __launch_bounds__(64) void make_eff_kernel(const float* __restrict__ qw, const float* __restrict__ qb,
                                                      const float* __restrict__ gyw, const float* __restrict__ gyb,
                                                      const float* __restrict__ kw, const float* __restrict__ kb,
                                                      const float* __restrict__ gxw, const float* __restrict__ gxb,
                                                      const float* __restrict__ part,
                                                      float* __restrict__ WeffQ, float* __restrict__ beffQ,
                                                      float* __restrict__ WeffK, float* __restrict__ beffK) {
    int id = blockIdx.x;
    int isK = id >> 7, b = (id >> 5) & 3, e = id & 31;
    const float* w     = isK ? kw  : qw;
    const float* bias  = isK ? kb  : qb;
    const float* gamma = isK ? gxw : gyw;
    const float* beta  = isK ? gxb : gyb;
    float inv_n = isK ? (1.f/32768.f) : (1.f/131072.f);
    float* W  = isK ? WeffK : WeffQ;
    float* be = isK ? beffK : beffQ;
    float partial = 0.f;
    for (int c = threadIdx.x; c < 256; c += 64) {
        int g = c >> 3, grp = b*32 + g;
        float s = 0.f, ss = 0.f;
        if (isK) {
            #pragma unroll
            for (int k2 = 0; k2 < 2; ++k2) {
                s  += part[(1024 + grp*2 + k2)*2 + 0];
                ss += part[(1024 + grp*2 + k2)*2 + 1];
            }
        } else {
            #pragma unroll
            for (int k2 = 0; k2 < 8; ++k2) {
                s  += part[(grp*8 + k2)*2 + 0];
                ss += part[(grp*8 + k2)*2 + 1];
            }
        }
        float mu = s * inv_n;
        float rs = rsqrtf(fmaf(-mu, mu, ss * inv_n) + EPSV);
        float wc = w[e*256 + c];
        float weff = wc * gamma[c] * rs;
        W[((size_t)b*256 + c)*32 + e] = weff;
        partial += wc * beta[c] - weff * mu;
    }
    for (int off = 32; off > 0; off >>= 1) partial += __shfl_down(partial, off);
    if (threadIdx.x == 0) be[b*32 + e] = partial + bias[e];
}

// ---------- fused 1x1 projection, flat 640-block grid ----------
// bid<512: y->q (b=bid>>7, 128 px-blocks); bid>=512: x->k (b=(bid-512)>>5, 32 px-blocks)
__global__ __launch_bounds__(256) void proj_kernel(const float* __restrict__ y, const float* __restrict__ x,
                                                   const float* __restrict__ WeffQ, const float* __restrict__ beffQ,
                                                   const float* __restrict__ WeffK, const float* __restrict__ beffK,
                                                   float* __restrict__ qbuf, float* __restrict__ kbuf) {
    int bid = blockIdx.x;
    int isX = bid >= 512;
    int lb = isX ? bid - 512 : bid;
    int b    = isX ? (lb >> 5) : (lb >> 7);
    int pxb  = isX ? (lb & 31) : (lb & 127);
    int npix = isX ? 4096 : 16384;
    const float* src   = isX ? x : y;
    const float* WeffT = isX ? WeffK : WeffQ;
    const float* beff  = isX ? beffK : beffQ;
    float* dst = isX ? kbuf : qbuf;

    int pix0 = pxb * 128 + (threadIdx.x & 63) * 2;
    int eg = __builtin_amdgcn_readfirstlane(threadIdx.x >> 6);
    const float* wp = WeffT + (size_t)b*256*32 + eg*8;
    float acc[2][8];
    #pragma unroll
    for (int j = 0; j < 8; ++j) {
        float bv = beff[b*32 + eg*8 + j];
        acc[0][j] = bv; acc[1][j] = bv;
    }
    const float* ysrc = src + (size_t)b*256*npix + pix0;
    #pragma unroll 8
    for (int c = 0; c < 256; ++c) {
        float2 t = *(const float2*)(ysrc + (size_t)c*npix);
        #pragma unroll
        for (int j = 0; j < 8; ++j) {
            float wj = wp[c*32 + j];
            acc[0][j] = fmaf(t.x, wj, acc[0][j]);
            acc[1][j] = fmaf(t.y, wj, acc[1][j]);
        }
    }
    float* dbase = dst + ((size_t)b*npix + pix0)*32 + eg*8;
    #pragma unroll
    for (int px = 0; px < 2; ++px) {
        float4 o0 = {acc[px][0], acc[px][1], acc[px][2], acc[px][3]};
        float4 o1 = {acc[px][4], acc[px][5], acc[px][6], acc[px][7]};
        *(float4*)(dbase + px*32 + 0) = o0;
        *(float4*)(dbase + px*32 + 4) = o1;
    }
}

// ---------- kernel A: attention weights ----------
// Block = 8x8 low-res tile, thread = child (tid = 32h+16u+2w+v).
// Writes attn maps TRANSPOSED [b][tile(64)][25 tap][256 child] so the gather
// kernel can read per-thread weights with coalesced global dword loads.
__global__ __launch_bounds__(256) void attn_weights_kernel(const float* __restrict__ q,   // [B][16384][32]
                                                           const float* __restrict__ kk,  // [B][4096][32]
                                                           float* __restrict__ g_attn)    // [B][64][25][256]
{
    __shared__ __align__(16) float sK[5184];   // [144 pos][36]
    __shared__ __align__(16) float sA[6400];   // [25 tap][256 child]
    int h0 = blockIdx.y * 8, w0 = blockIdx.x * 8;
    int b = blockIdx.z;
    int tid = threadIdx.x;

    // stage k halo: pos-major, stride 36
    for (int i = tid; i < 1152; i += 256) {
        int pos = i >> 3, e4 = i & 7;
        int r = pos / 12, c = pos - 12*r;
        int gh = h0 + r - 2, gw = w0 + c - 2;
        float4 v = make_float4(0.f, 0.f, 0.f, 0.f);
        if (gh >= 0 && gh < 64 && gw >= 0 && gw < 64)
            v = *(const float4*)(kk + (((size_t)b*4096 + gh*64 + gw)*32 + e4*4));
        *(float4*)&sK[pos*36 + e4*4] = v;
    }

    int h = tid >> 5, u = (tid >> 4) & 1, w = (tid >> 1) & 7, v = tid & 1;

    float qv[32];
    {
        int hh = 2*(h0 + h) + u, ww = 2*(w0 + w) + v;
        const float4* qp = (const float4*)(q + (((size_t)b*16384 + hh*128 + ww)*32));
        #pragma unroll
        for (int i4 = 0; i4 < 8; ++i4) {
            float4 t = qp[i4];
            qv[i4*4+0]=t.x; qv[i4*4+1]=t.y; qv[i4*4+2]=t.z; qv[i4*4+3]=t.w;
        }
    }
    __syncthreads();

    float a[25];
    const float* kbase = &sK[(h*12 + w)*36];
    #pragma unroll
    for (int j = 0; j < 25; ++j) {
        int dy = j / 5, dx = j - 5*dy;
        const float4* kp = (const float4*)(kbase + (dy*12 + dx)*36);
        float acc = 0.f;
        #pragma unroll
        for (int e4 = 0; e4 < 8; ++e4) {
            float4 kv = kp[e4];
            acc = fmaf(qv[e4*4+0], kv.x, acc);
            acc = fmaf(qv[e4*4+1], kv.y, acc);
            acc = fmaf(qv[e4*4+2], kv.z, acc);
            acc = fmaf(qv[e4*4+3], kv.w, acc);
        }
        a[j] = acc;
    }
    {
        float m = -1e30f;
        #pragma unroll
        for (int j = 0; j < 25; ++j) m = fmaxf(m, a[j]);
        float s = 0.f;
        #pragma unroll
        for (int j = 0; j < 25; ++j) { a[j] = __expf(a[j] - m); s += a[j]; }
        float inv = 1.f / s;
        // transposed store: tap-major, child-inner (conflict-free: lanes consecutive)
        #pragma unroll
        for (int j = 0; j < 25; ++j) sA[j*256 + tid] = a[j] * inv;
    }
    __syncthreads();

    // coalesced copy out: 6400 floats = 1600 float4
    float4* gdst = (float4*)(g_attn + ((size_t)b*64 + blockIdx.y*8 + blockIdx.x)*6400);
    const float4* ssrc = (const float4*)sA;
    for (int i = tid; i < 1600; i += 256) gdst[i] = ssrc[i];
}

// ---------- kernel B: weighted gather (fine-grained grid for occupancy) ----------
// grid (8,8,64): bz = b*16 + chunk(16 ch). Block = tile, thread = child.
// 16 channels per block: one sX staging, no chunk loop. LDS 11.5 KB, VGPR ~48
// -> 8 blocks/CU resident; 4096 blocks = 16 blocks/CU of work (tail amortized).
// Attn weights from global (transposed layout -> coalesced dword loads);
// attn buffer is 6.5 MB -> L2/L3 resident, re-reads nearly free.
// sX [144 pos][16 ch] stride 20 -> b128 reads <=2-way + 4-child broadcast.
__global__ __launch_bounds__(256) void gather_kernel(const float* __restrict__ g_attn, // [B][64][25][256]
                                                     const float* __restrict__ x,      // [B][256][64][64]
                                                     float* __restrict__ out)          // [B][256][128][128]
{
    __shared__ __align__(16) float sX[2880];   // 144*20
    int h0 = blockIdx.y * 8, w0 = blockIdx.x * 8;
    int b = blockIdx.z >> 4, chunk = blockIdx.z & 15;
    int tid = threadIdx.x;

    // per-thread attention weights: coalesced global loads (lane = child)
    float a[25];
    {
        const float* abase = g_attn + ((size_t)b*64 + blockIdx.y*8 + blockIdx.x)*6400 + tid;
        #pragma unroll
        for (int j = 0; j < 25; ++j) a[j] = abase[j*256];
    }

    // stage x chunk: 16 ch x 144 pos, pos-inner (coalesced global)
    for (int i = 0; i < 9; ++i) {
        int t = i*256 + tid;
        int cc = t / 144, pos = t - 144*cc;
        int r = pos / 12, cl = pos - 12*r;
        int gh = h0 + r - 2, gw = w0 + cl - 2;
        float val = 0.f;
        if (gh >= 0 && gh < 64 && gw >= 0 && gw < 64)
            val = x[(((size_t)b*256 + chunk*16 + cc)*64 + gh)*64 + gw];
        sX[pos*20 + cc] = val;
    }

    int h = tid >> 5, u = (tid >> 4) & 1, w = (tid >> 1) & 7, v = tid & 1;
    int hh = 2*(h0 + h) + u, ww = 2*(w0 + w) + v;
    int vbase = (h*12 + w)*20;
    __syncthreads();

    #pragma unroll
    for (int g = 0; g < 4; ++g) {
        float o0 = 0.f, o1 = 0.f, o2 = 0.f, o3 = 0.f;
        const float* xb = &sX[vbase + g*4];
        #pragma unroll
        for (int j = 0; j < 25; ++j) {
            int dy = j / 5, dx = j - 5*dy;
            float4 xv = *(const float4*)(xb + (dy*12 + dx)*20);
            float aw = a[j];
            o0 = fmaf(aw, xv.x, o0);
            o1 = fmaf(aw, xv.y, o1);
            o2 = fmaf(aw, xv.z, o2);
            o3 = fmaf(aw, xv.w, o3);
        }
        size_t ob = (((size_t)b*256 + chunk*16 + g*4)*128 + hh)*128 + ww;
        out[ob]           = o0;
        out[ob + 16384]   = o1;
        out[ob + 32768]   = o2;
        out[ob + 49152]   = o3;
    }
}

extern "C" void kernel_launch(void* const* d_in, const int* in_sizes, int n_in,
                              void* d_out, int out_size, void* d_ws, size_t ws_size,
                              hipStream_t stream) {
    const float* y   = (const float*)d_in[0];
    const float* x   = (const float*)d_in[1];
    const float* gyw = (const float*)d_in[2];
    const float* gyb = (const float*)d_in[3];
    const float* gxw = (const float*)d_in[4];
    const float* gxb = (const float*)d_in[5];
    const float* qw  = (const float*)d_in[6];
    const float* qb  = (const float*)d_in[7];
    const float* kw  = (const float*)d_in[8];
    const float* kb  = (const float*)d_in[9];
    float* out = (float*)d_out;
    float* ws  = (float*)d_ws;

    float* part   = ws;              // 2560
    float* WeffQ  = ws + 2560;       // 32768
    float* beffQ  = ws + 35328;      // 128
    float* WeffK  = ws + 35456;      // 32768
    float* beffK  = ws + 68224;      // 128
    float* qbuf   = ws + 68352;      // 4*16384*32 = 2097152
    float* kbuf   = ws + 2165504;    // 4*4096*32  = 524288
    float* attnbf = ws + 2689792;    // 4*64*6400  = 1638400  (total ~17.3 MB)

    stats_kernel<<<1280, 256, 0, stream>>>(y, x, part);
    make_eff_kernel<<<256, 64, 0, stream>>>(qw, qb, gyw, gyb, kw, kb, gxw, gxb,
                                            part, WeffQ, beffQ, WeffK, beffK);
    proj_kernel<<<640, 256, 0, stream>>>(y, x, WeffQ, beffQ, WeffK, beffK, qbuf, kbuf);
    attn_weights_kernel<<<dim3(8, 8, 4), 256, 0, stream>>>(qbuf, kbuf, attnbf);
    gather_kernel<<<dim3(8, 8, 64), 256, 0, stream>>>(attnbf, x, out);
}